// Round 1
// baseline (2149.817 us; speedup 1.0000x reference)
//
#include <hip/hip_runtime.h>

// DeepRationalNeuralFingerprintHidden — fused f32 baseline.
// B=2048, A=128, D=5, Fa=62, Fb=6, C=256, Fin=68, rows N = 262144.
//
// One kernel: gather (neighbor-sum + bond-sum -> Hs[64][68..80 zero-padded])
// then 5 fused dense+rational layers with the h-tile resident in LDS.
// Block = 256 threads, tile = 64 rows x 256 cols, per-thread 8x8 accumulators
// (cols split as [cg*4 .. +3] and [128+cg*4 .. +3] so W ds_read_b128 is
// bank-conflict-free: 32 lanes x 16B = contiguous 512B across all 32 banks).

#define TILE_M 64
#define KC 16
#define NTHREADS 256

__global__ __launch_bounds__(NTHREADS, 2)
void drnf_fused_kernel(const float* __restrict__ atoms,
                       const float* __restrict__ bonds,
                       const int*   __restrict__ edges,
                       const float* __restrict__ exist,
                       const float* __restrict__ W1, const float* __restrict__ B1,
                       const float* __restrict__ W2, const float* __restrict__ B2,
                       const float* __restrict__ W3, const float* __restrict__ B3,
                       const float* __restrict__ W4, const float* __restrict__ B4,
                       const float* __restrict__ W5, const float* __restrict__ B5,
                       const float* __restrict__ alphas, const float* __restrict__ betas,
                       float* __restrict__ out)
{
    __shared__ float Hs[TILE_M][256];   // 64 KB: h tile (layer input)
    __shared__ float Ws[KC][256];       // 16 KB: staged W chunk

    const int tid  = threadIdx.x;
    const int row0 = blockIdx.x * TILE_M;

    // ---------------- gather phase ----------------
    {
        const int r   = tid >> 2;        // 0..63 (row within tile)
        const int p   = tid & 3;         // 4 threads per row
        const int row = row0 + r;
        const int b   = row >> 7;        // /A (A=128)
        const int a   = row & 127;
        const float* abase = atoms + (size_t)b * (128 * 62);
        const float* arow  = abase + (size_t)a * 62;
        const int*   eg    = edges + (size_t)row * 5;

        const int e0 = eg[0], e1 = eg[1], e2 = eg[2], e3 = eg[3], e4 = eg[4];
        const int i0 = (e0 >= 0) ? e0 : 0;
        const int i1 = (e1 >= 0) ? e1 : 0;
        const int i2 = (e2 >= 0) ? e2 : 0;
        const int i3 = (e3 >= 0) ? e3 : 0;
        const int i4 = (e4 >= 0) ? e4 : 0;

        for (int f = p; f < 62; f += 4) {
            float s = arow[f];
            s += (e0 >= 0) ? abase[i0 * 62 + f] : 0.0f;
            s += (e1 >= 0) ? abase[i1 * 62 + f] : 0.0f;
            s += (e2 >= 0) ? abase[i2 * 62 + f] : 0.0f;
            s += (e3 >= 0) ? abase[i3 * 62 + f] : 0.0f;
            s += (e4 >= 0) ? abase[i4 * 62 + f] : 0.0f;
            Hs[r][f] = s;
        }
        const float* brow = bonds + (size_t)row * 30;   // D*Fb = 30
        for (int f = p; f < 6; f += 4) {
            Hs[r][62 + f] = brow[f] + brow[6 + f] + brow[12 + f] + brow[18 + f] + brow[24 + f];
        }
        // zero-pad cols 68..79 so the padded k-chunk of layer 1 reads clean zeros
        for (int f = 68 + p; f < 80; f += 4) Hs[r][f] = 0.0f;
    }

    // ---------------- layer phase ----------------
    const int rg    = tid >> 5;        // 0..7 : row group (8 rows each)
    const int cg    = tid & 31;        // 0..31: col group
    const int rbase = rg * 8;
    const int cA    = cg * 4;          // cols cA..cA+3
    const int cB    = 128 + cg * 4;    // cols cB..cB+3

    const float* Wp[5] = {W1, W2, W3, W4, W5};
    const float* bp[5] = {B1, B2, B3, B4, B5};
    const int    Kp[5] = {68, 256, 256, 256, 256};

#pragma unroll
    for (int L = 0; L < 5; ++L) {
        const int K   = Kp[L];
        const int nch = (K + KC - 1) / KC;

        const float a0 = alphas[L * 4 + 0], a1 = alphas[L * 4 + 1];
        const float a2 = alphas[L * 4 + 2], a3 = alphas[L * 4 + 3];
        const float q0 = betas[L * 3 + 0], q1 = betas[L * 3 + 1], q2 = betas[L * 3 + 2];

        float bias[8];
#pragma unroll
        for (int j = 0; j < 4; ++j) bias[j]     = bp[L][cA + j];
#pragma unroll
        for (int j = 0; j < 4; ++j) bias[4 + j] = bp[L][cB + j];

        float acc[8][8];
#pragma unroll
        for (int i = 0; i < 8; ++i)
#pragma unroll
            for (int j = 0; j < 8; ++j) acc[i][j] = 0.0f;

        for (int ch = 0; ch < nch; ++ch) {
            const int k0 = ch * KC;
            __syncthreads();   // Ws reuse-safe + Hs updated (prev epilogue done)

            // stage W[k0..k0+15][:] -> Ws (zero-fill rows >= K; only layer 1 hits it)
#pragma unroll
            for (int i = 0; i < (KC * 256 / 4) / NTHREADS; ++i) {  // 4 float4 per thread
                const int flat = tid + i * NTHREADS;  // float4 index within chunk
                const int kr   = flat >> 6;
                const int kc   = (flat & 63) << 2;
                const int gk   = k0 + kr;
                float4 v = make_float4(0.0f, 0.0f, 0.0f, 0.0f);
                if (gk < K) v = *(const float4*)(Wp[L] + (size_t)gk * 256 + kc);
                *(float4*)&Ws[kr][kc] = v;
            }
            __syncthreads();

#pragma unroll
            for (int kk = 0; kk < KC; kk += 4) {
                float4 xq[8];
#pragma unroll
                for (int i = 0; i < 8; ++i)
                    xq[i] = *(const float4*)&Hs[rbase + i][k0 + kk];   // 2-addr broadcast

#pragma unroll
                for (int t = 0; t < 4; ++t) {
                    const float4 w0 = *(const float4*)&Ws[kk + t][cA]; // conflict-free b128
                    const float4 w1 = *(const float4*)&Ws[kk + t][cB];
                    const float wv[8] = {w0.x, w0.y, w0.z, w0.w, w1.x, w1.y, w1.z, w1.w};
#pragma unroll
                    for (int i = 0; i < 8; ++i) {
                        const float xv = (t == 0) ? xq[i].x : (t == 1) ? xq[i].y
                                       : (t == 2) ? xq[i].z : xq[i].w;
#pragma unroll
                        for (int j = 0; j < 8; ++j)
                            acc[i][j] = fmaf(xv, wv[j], acc[i][j]);
                    }
                }
            }
        }
        __syncthreads();  // everyone done reading Hs for this layer

        // epilogue: bias + rational activation; write back (or out on last layer)
        if (L < 4) {
#pragma unroll
            for (int i = 0; i < 8; ++i) {
#pragma unroll
                for (int j = 0; j < 8; ++j) {
                    const float x  = acc[i][j] + bias[j];
                    const float pn = fmaf(fmaf(fmaf(a0, x, a1), x, a2), x, a3);
                    const float qd = fmaf(fmaf(q0, x, q1), x, q2);   // >= 1 for given betas
                    float rr = __builtin_amdgcn_rcpf(qd);
                    rr = rr * (2.0f - qd * rr);                      // Newton -> ~fp32
                    const int col = (j < 4) ? (cA + j) : (cB + j - 4);
                    Hs[rbase + i][col] = pn * rr;
                }
            }
        } else {
#pragma unroll
            for (int i = 0; i < 8; ++i) {
                const int row = row0 + rbase + i;
                const float ex = exist[row];
                float res[8];
#pragma unroll
                for (int j = 0; j < 8; ++j) {
                    const float x  = acc[i][j] + bias[j];
                    const float pn = fmaf(fmaf(fmaf(a0, x, a1), x, a2), x, a3);
                    const float qd = fmaf(fmaf(q0, x, q1), x, q2);
                    float rr = __builtin_amdgcn_rcpf(qd);
                    rr = rr * (2.0f - qd * rr);
                    res[j] = pn * rr * ex;
                }
                float4* dstA = (float4*)(out + (size_t)row * 256 + cA);
                float4* dstB = (float4*)(out + (size_t)row * 256 + cB);
                *dstA = make_float4(res[0], res[1], res[2], res[3]);
                *dstB = make_float4(res[4], res[5], res[6], res[7]);
            }
        }
    }
}

extern "C" void kernel_launch(void* const* d_in, const int* in_sizes, int n_in,
                              void* d_out, int out_size, void* d_ws, size_t ws_size,
                              hipStream_t stream) {
    const float* atoms  = (const float*)d_in[0];
    const float* bonds  = (const float*)d_in[1];
    const int*   edges  = (const int*)d_in[2];
    const float* exist  = (const float*)d_in[3];
    const float* W1 = (const float*)d_in[4];
    const float* B1 = (const float*)d_in[5];
    const float* W2 = (const float*)d_in[6];
    const float* B2 = (const float*)d_in[7];
    const float* W3 = (const float*)d_in[8];
    const float* B3 = (const float*)d_in[9];
    const float* W4 = (const float*)d_in[10];
    const float* B4 = (const float*)d_in[11];
    const float* W5 = (const float*)d_in[12];
    const float* B5 = (const float*)d_in[13];
    const float* alphas = (const float*)d_in[14];
    const float* betas  = (const float*)d_in[15];
    float* out = (float*)d_out;

    const int n_rows = 2048 * 128;           // B*A
    const int grid   = n_rows / TILE_M;      // 4096

    drnf_fused_kernel<<<grid, NTHREADS, 0, stream>>>(
        atoms, bonds, edges, exist,
        W1, B1, W2, B2, W3, B3, W4, B4, W5, B5,
        alphas, betas, out);
}

// Round 5
// 1132.590 us; speedup vs baseline: 1.8981x; 1.8981x over previous
//
#include <hip/hip_runtime.h>

// DeepRationalNeuralFingerprintHidden — split-bf16 MFMA version (r2: fix
// constant-bus violation by forcing activation coeffs into VGPRs).
// B=2048, A=128, D=5, Fa=62, Fb=6, C=256, rows N=262144.
//
// Prologue kernel: transpose+split W_l (f32 [K][256]) -> WT_hi/WT_lo bf16
// [l][n][k] (k-contiguous per n) in d_ws. Main kernel: gather -> Hs hi/lo
// bf16 planes in LDS; 5 fused layers, each: stage WsT 32-k chunk via
// global_load_lds (16B), then mfma_f32_16x16x32_bf16 with
// D = W^T · h^T  (A-frag from WsT, B-frag from Hs, both k-contiguous;
// D reg-quad = 4 consecutive n for one m-row -> vector epilogue writes).
// Split product: hi*hi + lo*hi + hi*lo (drop lo*lo, ~2^-17 rel).

typedef __attribute__((ext_vector_type(8))) short short8v;
typedef __attribute__((ext_vector_type(4))) short short4v;
typedef __attribute__((ext_vector_type(4))) float f32x4;

#define THREADS 512
#define TILE_M 64
#define KC 32
#define HS_LD 264   // 256 + 8 bf16 pad: row shift = 4 banks -> 8 words/bank (min)

__device__ __forceinline__ unsigned short f2bf(float x) {
    unsigned u = __builtin_bit_cast(unsigned, x);
    u += 0x7FFFu + ((u >> 16) & 1u);          // RNE
    return (unsigned short)(u >> 16);
}
__device__ __forceinline__ float bf2f(unsigned short h) {
    return __builtin_bit_cast(float, (unsigned)h << 16);
}
// Force a wave-uniform float into a VGPR so v_fma_f32 never sees two SGPR
// operands (constant-bus restriction: max 1 SGPR read per VOP instr).
__device__ __forceinline__ float to_vgpr(float x) {
    float y;
    asm("v_mov_b32 %0, %1" : "=v"(y) : "s"(x));
    return y;
}

// ---------------- prologue: W -> WT hi/lo bf16, transposed ----------------
__global__ void drnf_wprep(const float* __restrict__ W1, const float* __restrict__ W2,
                           const float* __restrict__ W3, const float* __restrict__ W4,
                           const float* __restrict__ W5,
                           unsigned short* __restrict__ wtHi,
                           unsigned short* __restrict__ wtLo) {
    const int flat = blockIdx.x * blockDim.x + threadIdx.x;  // 5*256*32 = 40960
    const int n  = flat & 255;
    const int kg = (flat >> 8) & 31;
    const int l  = flat >> 13;
    const float* W = (l == 0) ? W1 : (l == 1) ? W2 : (l == 2) ? W3 : (l == 3) ? W4 : W5;
    const int K = (l == 0) ? 68 : 256;

    short8v vh, vl;
#pragma unroll
    for (int j = 0; j < 8; ++j) {
        const int k = kg * 8 + j;
        const float v = (k < K) ? W[(size_t)k * 256 + n] : 0.0f;   // coalesced over n
        const unsigned short h = f2bf(v);
        vh[j] = (short)h;
        vl[j] = (short)f2bf(v - bf2f(h));
    }
    const size_t o = ((size_t)(l * 256 + n)) * 256 + (size_t)kg * 8;
    *(short8v*)(wtHi + o) = vh;
    *(short8v*)(wtLo + o) = vl;
}

// ---------------- main fused kernel ----------------
__global__ __launch_bounds__(THREADS, 2)
void drnf_mfma(const float* __restrict__ atoms,
               const float* __restrict__ bonds,
               const int*   __restrict__ edges,
               const float* __restrict__ exist,
               const float* __restrict__ B1, const float* __restrict__ B2,
               const float* __restrict__ B3, const float* __restrict__ B4,
               const float* __restrict__ B5,
               const float* __restrict__ alphas, const float* __restrict__ betas,
               const unsigned short* __restrict__ wtHi,
               const unsigned short* __restrict__ wtLo,
               float* __restrict__ out)
{
    __shared__ unsigned short HsHi[TILE_M][HS_LD];   // 33,792 B
    __shared__ unsigned short HsLo[TILE_M][HS_LD];   // 33,792 B
    __shared__ unsigned short WsHi[256][KC];         // 16,384 B
    __shared__ unsigned short WsLo[256][KC];         // 16,384 B  (total ~100 KB)

    const int tid  = threadIdx.x;
    const int row0 = blockIdx.x * TILE_M;

    // ---------- gather: h0 = [atoms + neigh-sum | bond-sum], split hi/lo ----------
    {
        const int r = tid >> 3;          // 0..63
        const int p = tid & 7;
        const int row = row0 + r;
        const int bb = row >> 7;
        const int aa = row & 127;
        const float* abase = atoms + (size_t)bb * (128 * 62);
        const float* arow  = abase + (size_t)aa * 62;
        const int*   eg    = edges + (size_t)row * 5;

        const int e0 = eg[0], e1 = eg[1], e2 = eg[2], e3 = eg[3], e4 = eg[4];
        const int i0 = (e0 >= 0) ? e0 : 0, i1 = (e1 >= 0) ? e1 : 0;
        const int i2 = (e2 >= 0) ? e2 : 0, i3 = (e3 >= 0) ? e3 : 0;
        const int i4 = (e4 >= 0) ? e4 : 0;

        for (int f = p; f < 62; f += 8) {
            float s = arow[f];
            s += (e0 >= 0) ? abase[i0 * 62 + f] : 0.0f;
            s += (e1 >= 0) ? abase[i1 * 62 + f] : 0.0f;
            s += (e2 >= 0) ? abase[i2 * 62 + f] : 0.0f;
            s += (e3 >= 0) ? abase[i3 * 62 + f] : 0.0f;
            s += (e4 >= 0) ? abase[i4 * 62 + f] : 0.0f;
            const unsigned short h = f2bf(s);
            HsHi[r][f] = h;
            HsLo[r][f] = f2bf(s - bf2f(h));
        }
        if (p < 6) {
            const float* brow = bonds + (size_t)row * 30;
            const float s = brow[p] + brow[6 + p] + brow[12 + p] + brow[18 + p] + brow[24 + p];
            const unsigned short h = f2bf(s);
            HsHi[r][62 + p] = h;
            HsLo[r][62 + p] = f2bf(s - bf2f(h));
        }
        for (int f = 68 + p; f < 96; f += 8) { HsHi[r][f] = 0; HsLo[r][f] = 0; }
    }

    // ---------- wave geometry ----------
    const int l    = tid & 63;
    const int w    = tid >> 6;           // 0..7
    const int l15  = l & 15;
    const int g    = l >> 4;             // 0..3
    const int g8   = g * 8;
    const int nbase = (w >> 1) * 64;     // 4 n-tiles of 16
    const int mbase = (w & 1) * 32;      // 2 m-tiles of 16

    const float* bptr[5] = {B1, B2, B3, B4, B5};
    const int    nchs[5] = {3, 8, 8, 8, 8};     // K chunks of 32 (L0 padded to 96)

#pragma unroll
    for (int L = 0; L < 5; ++L) {
        f32x4 acc[4][2];
#pragma unroll
        for (int nt = 0; nt < 4; ++nt)
#pragma unroll
            for (int mt = 0; mt < 2; ++mt)
                acc[nt][mt] = (f32x4)0.0f;

        const int nch = nchs[L];
        const size_t wofs = (size_t)L * 65536;

        for (int ch = 0; ch < nch; ++ch) {
            const int k0 = ch * KC;
            __syncthreads();   // prior compute done reading WsT (+ Hs ready)

            // stage WT chunk (32 KB) linearly via global_load_lds width=16
#pragma unroll
            for (int r2 = 0; r2 < 2; ++r2) {
                const int i    = r2 * 512 + tid;    // tid = w*64 + l
                const int n    = i >> 2;
                const int slot = i & 3;
                const unsigned short* gHi = wtHi + wofs + (size_t)n * 256 + k0 + slot * 8;
                const unsigned short* gLo = wtLo + wofs + (size_t)n * 256 + k0 + slot * 8;
                unsigned short* dHi = &WsHi[0][0] + (r2 * 8 + w) * 512;  // wave-uniform
                unsigned short* dLo = &WsLo[0][0] + (r2 * 8 + w) * 512;
                __builtin_amdgcn_global_load_lds(
                    (const __attribute__((address_space(1))) void*)gHi,
                    (__attribute__((address_space(3))) void*)dHi, 16, 0, 0);
                __builtin_amdgcn_global_load_lds(
                    (const __attribute__((address_space(1))) void*)gLo,
                    (__attribute__((address_space(3))) void*)dLo, 16, 0, 0);
            }
            __syncthreads();   // drains vmcnt; WsT + Hs visible

            // ---- one K=32 step: B-frags (h), then n-tiles: A-frags (W^T) + 6 mfma ----
            short8v bh[2], bl[2];
#pragma unroll
            for (int mt = 0; mt < 2; ++mt) {
                const int m = mbase + mt * 16 + l15;
                bh[mt] = *(const short8v*)&HsHi[m][k0 + g8];
                bl[mt] = *(const short8v*)&HsLo[m][k0 + g8];
            }
#pragma unroll
            for (int nt = 0; nt < 4; ++nt) {
                const int n = nbase + nt * 16 + l15;
                const short8v ah = *(const short8v*)&WsHi[n][g8];
                const short8v al = *(const short8v*)&WsLo[n][g8];
                acc[nt][0] = __builtin_amdgcn_mfma_f32_16x16x32_bf16(ah, bh[0], acc[nt][0], 0, 0, 0);
                acc[nt][1] = __builtin_amdgcn_mfma_f32_16x16x32_bf16(ah, bh[1], acc[nt][1], 0, 0, 0);
                acc[nt][0] = __builtin_amdgcn_mfma_f32_16x16x32_bf16(al, bh[0], acc[nt][0], 0, 0, 0);
                acc[nt][1] = __builtin_amdgcn_mfma_f32_16x16x32_bf16(al, bh[1], acc[nt][1], 0, 0, 0);
                acc[nt][0] = __builtin_amdgcn_mfma_f32_16x16x32_bf16(ah, bl[0], acc[nt][0], 0, 0, 0);
                acc[nt][1] = __builtin_amdgcn_mfma_f32_16x16x32_bf16(ah, bl[1], acc[nt][1], 0, 0, 0);
            }
        }
        __syncthreads();   // all waves done reading Hs(h_L) before overwrite

        // ---------- epilogue: bias + rational, write h_{L+1} (or out) ----------
        const float a0 = to_vgpr(alphas[L * 4 + 0]), a1 = to_vgpr(alphas[L * 4 + 1]);
        const float a2 = to_vgpr(alphas[L * 4 + 2]), a3 = to_vgpr(alphas[L * 4 + 3]);
        const float q0 = to_vgpr(betas[L * 3 + 0]), q1 = to_vgpr(betas[L * 3 + 1]);
        const float q2 = to_vgpr(betas[L * 3 + 2]);

        if (L < 4) {
#pragma unroll
            for (int nt = 0; nt < 4; ++nt) {
                const int n4 = nbase + nt * 16 + g * 4;     // 4 consecutive n
                const f32x4 bs = *(const f32x4*)(bptr[L] + n4);
#pragma unroll
                for (int mt = 0; mt < 2; ++mt) {
                    const int m = mbase + mt * 16 + l15;
                    short4v vh, vl;
#pragma unroll
                    for (int j = 0; j < 4; ++j) {
                        const float x  = acc[nt][mt][j] + bs[j];
                        const float pn = fmaf(fmaf(fmaf(a0, x, a1), x, a2), x, a3);
                        const float qd = fmaf(fmaf(q0, x, q1), x, q2);
                        float rr = __builtin_amdgcn_rcpf(qd);
                        rr = rr * (2.0f - qd * rr);
                        const float h  = pn * rr;
                        const unsigned short hh = f2bf(h);
                        vh[j] = (short)hh;
                        vl[j] = (short)f2bf(h - bf2f(hh));
                    }
                    *(short4v*)&HsHi[m][n4] = vh;   // 8B aligned (n4 % 4 == 0)
                    *(short4v*)&HsLo[m][n4] = vl;
                }
            }
        } else {
#pragma unroll
            for (int mt = 0; mt < 2; ++mt) {
                const int m  = mbase + mt * 16 + l15;
                const float ex = exist[row0 + m];
#pragma unroll
                for (int nt = 0; nt < 4; ++nt) {
                    const int n4 = nbase + nt * 16 + g * 4;
                    const f32x4 bs = *(const f32x4*)(bptr[4] + n4);
                    f32x4 o;
#pragma unroll
                    for (int j = 0; j < 4; ++j) {
                        const float x  = acc[nt][mt][j] + bs[j];
                        const float pn = fmaf(fmaf(fmaf(a0, x, a1), x, a2), x, a3);
                        const float qd = fmaf(fmaf(q0, x, q1), x, q2);
                        float rr = __builtin_amdgcn_rcpf(qd);
                        rr = rr * (2.0f - qd * rr);
                        o[j] = pn * rr * ex;
                    }
                    *(f32x4*)(out + (size_t)(row0 + m) * 256 + n4) = o;
                }
            }
        }
    }
}

extern "C" void kernel_launch(void* const* d_in, const int* in_sizes, int n_in,
                              void* d_out, int out_size, void* d_ws, size_t ws_size,
                              hipStream_t stream) {
    const float* atoms = (const float*)d_in[0];
    const float* bonds = (const float*)d_in[1];
    const int*   edges = (const int*)d_in[2];
    const float* exist = (const float*)d_in[3];
    const float* W1 = (const float*)d_in[4];
    const float* B1 = (const float*)d_in[5];
    const float* W2 = (const float*)d_in[6];
    const float* B2 = (const float*)d_in[7];
    const float* W3 = (const float*)d_in[8];
    const float* B3 = (const float*)d_in[9];
    const float* W4 = (const float*)d_in[10];
    const float* B4 = (const float*)d_in[11];
    const float* W5 = (const float*)d_in[12];
    const float* B5 = (const float*)d_in[13];
    const float* alphas = (const float*)d_in[14];
    const float* betas  = (const float*)d_in[15];
    float* out = (float*)d_out;

    unsigned short* wtHi = (unsigned short*)d_ws;
    unsigned short* wtLo = wtHi + (size_t)5 * 256 * 256;   // needs 1.31 MB of ws

    // prologue: 5*256*32 threads
    drnf_wprep<<<160, 256, 0, stream>>>(W1, W2, W3, W4, W5, wtHi, wtLo);

    const int n_rows = 2048 * 128;
    const int grid   = n_rows / TILE_M;   // 4096
    drnf_mfma<<<grid, THREADS, 0, stream>>>(
        atoms, bonds, edges, exist,
        B1, B2, B3, B4, B5, alphas, betas,
        wtHi, wtLo, out);
}